// Round 5
// baseline (168.336 us; speedup 1.0000x reference)
//
#include <hip/hip_runtime.h>
#include <hip/hip_fp16.h>

// DiffusionConv: out = x@Tf0 + Px@(Tb0+Tb1) + P2x@(Tf1+Tb2) + P3x@Tf2
// R19: props are the elephant (~40us each, hiding under the 45us fill top-5
// cutoff; accounting via R17's 48us scatter datapoint). Cause: random 128B
// row gathers from a 6.4MB table > 4MB per-XCD L2, L3 poisoned each iter ->
// all-miss latency + ~100MB thrash traffic per prop.
// Fix: split every feature table into two [N][32] halves (3.2MB < L2).
// Each prop = 2*PB blocks; lo blocks do ch 0-31, hi blocks ch 32-63;
// dispatch order phase-separates them so the gather table is L2-resident.
//  - prop1 decodes w*dinv[col] into bkt2 (lo blocks write; no race).
//  - gemm un-fused back to its own dispatch (needs both halves done).
//  - scatter2 conversion + gemm A-loads use the split layout.
// scatter2/build unchanged from verified R18 (EPB 8192, sparse dump).

#define N_NODES 50000
#define N_EDGES 800000
#define C 64
#define CAP 64          // bucket capacity; rows ~ Poisson(16), P(>64) ~ 2e-18
#define NPART 196       // partitions of 256 rows: p = r >> 8
#define CAPP 4608       // edges per partition region; mean 4096, +8 sigma
#define EPB 8192        // edges per block in scatter2
#define NEB 98          // ceil(800000/8192)
#define XH_BLOCKS 782   // ceil(800000 float4 chunks / 1024)
#define CW_BLOCKS 16    // 16384 weight elems / 1024
#define PB 3125         // node tiles of 16: 50000/16 exactly
#define GB 782          // ceil(50000/64) gemm row-tiles

typedef _Float16 half8 __attribute__((ext_vector_type(8)));
typedef float f32x4 __attribute__((ext_vector_type(4)));

// Fused: blocks [0,NEB): hist+reserve+scatter; [NEB,NEB+XH): x fp32->fp16
// into SPLIT tables xh0/xh1 ([N][32] each); [NEB+XH,..): combined weights
// -> fp16 transposed whc[j][co][ci]
__global__ __launch_bounds__(1024) void scatter2_kernel(
        const int* __restrict__ row, const int* __restrict__ col,
        const float* __restrict__ w, int* __restrict__ percur,
        uint2* __restrict__ pedges,
        const float* __restrict__ x, __half* __restrict__ xh0,
        __half* __restrict__ xh1,
        const float* __restrict__ tf, const float* __restrict__ tb,
        _Float16* __restrict__ whc) {
    const int tid = threadIdx.x;
    if (blockIdx.x >= NEB + XH_BLOCKS) {
        int idx = (blockIdx.x - NEB - XH_BLOCKS) * 1024 + tid;  // < 16384
        int j = idx >> 12;
        int rem = idx & 4095;   // ci*64 + co
        int ci = rem >> 6;
        int co = rem & 63;
        float v;
        if (j == 0)      v = tf[rem];                         // Tf0
        else if (j == 1) v = tb[rem] + tb[4096 + rem];        // Tb0 + Tb1
        else if (j == 2) v = tf[4096 + rem] + tb[8192 + rem]; // Tf1 + Tb2
        else             v = tf[8192 + rem];                  // Tf2
        whc[(j << 12) + (co << 6) + ci] = (_Float16)v;        // transposed
        return;
    }
    if (blockIdx.x >= NEB) {
        int i = (blockIdx.x - NEB) * 1024 + tid;
        if (i < N_NODES * C / 4) {
            float4 v = ((const float4*)x)[i];
            union { float2 f2; __half2 h2[2]; } u;
            u.h2[0] = __floats2half2_rn(v.x, v.y);
            u.h2[1] = __floats2half2_rn(v.z, v.w);
            int node = i >> 4;
            int ci0 = (i & 15) << 2;           // 0..60
            __half* dst = (ci0 < 32) ? (xh0 + node * 32 + ci0)
                                     : (xh1 + node * 32 + (ci0 - 32));
            *(float2*)(void*)dst = u.f2;
        }
        return;
    }
    __shared__ int h[NPART];
    __shared__ int cur[NPART];
    uint2 ent[8];
    int pp[8];
    if (tid < NPART) h[tid] = 0;
    __syncthreads();
    int base = blockIdx.x * EPB;
#pragma unroll
    for (int i = 0; i < 8; ++i) {
        int e = base + i * 1024 + tid;
        pp[i] = -1;
        if (e < N_EDGES) {
            int r = row[e];
            unsigned int c = (unsigned int)col[e];
            unsigned int wh = (unsigned int)__half_as_ushort(__float2half_rn(w[e]));
            ent[i] = make_uint2((c << 16) | wh, (unsigned int)(r & 255));
            pp[i] = r >> 8;
            atomicAdd(&h[pp[i]], 1);
        }
    }
    __syncthreads();
    if (tid < NPART) cur[tid] = atomicAdd(&percur[tid], h[tid]);
    __syncthreads();
#pragma unroll
    for (int i = 0; i < 8; ++i) {
        if (pp[i] >= 0) {
            int slot = atomicAdd(&cur[pp[i]], 1);
            pedges[(size_t)pp[i] * CAPP + slot] = ent[i];
        }
    }
}

// One block per partition: LDS-bin 256 rows x 64 slots, fuse dinv,
// dump only the used slot prefix per row (uint4 chunks).
__global__ __launch_bounds__(1024) void build_kernel(
        const uint2* __restrict__ pedges, const int* __restrict__ percur,
        unsigned int* __restrict__ bkt, int* __restrict__ cnt,
        float* __restrict__ dinv) {
    __shared__ unsigned int lbuck[256 * CAP];   // 64 KB
    __shared__ int lcnt[256];
    const int tid = threadIdx.x;
    const int p = blockIdx.x;
    if (tid < 256) lcnt[tid] = 0;
    __syncthreads();
    int e = min(percur[p], CAPP);
    const uint2* src = pedges + (size_t)p * CAPP;
    for (int i = tid; i < e; i += 1024) {
        uint2 en = src[i];
        int rl = (int)en.y;
        int slot = atomicAdd(&lcnt[rl], 1);
        if (slot < CAP) lbuck[(rl << 6) + slot] = en.x;
    }
    __syncthreads();
    if (tid < 256) {
        int m = min(lcnt[tid], CAP);
        int g = (p << 8) + tid;
        float sum = 0.f;
        for (int j = 0; j < m; ++j)
            sum += __half2float(__ushort_as_half(
                (unsigned short)(lbuck[(tid << 6) + j] & 0xFFFFu)));
        if (g < N_NODES) {
            cnt[g] = m;
            dinv[g] = (sum > 0.f) ? rsqrtf(sum) : 0.f;
        }
    }
    __syncthreads();
    // sparse dump: 4 threads per row, chunk = tid&3; only ceil(m/4) uint4s
    {
        int r = tid >> 2;
        int ch = tid & 3;
        int m = min(lcnt[r], CAP);
        const uint4* s4 = (const uint4*)&lbuck[r << 6];
        uint4* dst = (uint4*)(bkt + (((size_t)(p << 8) + r) << 6));
        for (int j = ch; (j << 2) < m; j += 4) dst[j] = s4[j];
    }
}

// Split-table prop: grid = 2*PB blocks. Blocks [0,PB): channel half 0
// (table xin0, out xout0); [PB,2PB): half 1. Per block 16 nodes, 4 waves;
// quarter q owns node tile*16 + wib*4 + q; lane ql (0-15) holds 2 channels
// (2*ql, 2*ql+1) of the half => gather = 4B/lane, 64B row in L2-resident
// 3.2MB slice.
// FIRST: decode nn = w*dinv[col] from bkt; lo blocks also write decoded
// entries to bkt2 (read by later props -- no dinv gather there).
template <bool FIRST>
__global__ __launch_bounds__(256) void prop_kernel(
        const __half* __restrict__ xin0, const __half* __restrict__ xin1,
        __half* __restrict__ xout0, __half* __restrict__ xout1,
        const int* __restrict__ cnt, const unsigned int* __restrict__ bkt,
        unsigned int* __restrict__ bkt2, const float* __restrict__ dinv) {
    const int bid = blockIdx.x;
    const int h = (bid >= PB) ? 1 : 0;
    const int tb = bid - (h ? PB : 0);
    const __half* __restrict__ xin = h ? xin1 : xin0;
    __half* __restrict__ xout = h ? xout1 : xout0;
    const int tid = threadIdx.x;
    const int wib = tid >> 6;
    const int lane = tid & 63;
    const int q = lane >> 4;
    const int ql = lane & 15;
    const int node = (tb << 4) + (wib << 2) + q;   // < 50000 always
    int m = min(cnt[node], CAP);
    int base = node << 6;
    // prefetch all (<=4) strided bucket entries for this lane
    int cj[4];
    float nj[4];
#pragma unroll
    for (int s = 0; s < 4; ++s) {
        int idx = (s << 4) + ql;
        cj[s] = 0;
        nj[s] = 0.f;
        if (idx < m) {
            unsigned int b = bkt[base + idx];
            int c = (int)(b >> 16);
            cj[s] = c << 5;                        // half-elem offset in 32-wide table
            float wv = __half2float(__ushort_as_half((unsigned short)(b & 0xFFFFu)));
            if constexpr (FIRST) {
                float nn = wv * dinv[c];
                nj[s] = nn;
                if (h == 0)
                    bkt2[base + idx] = ((unsigned int)c << 16) |
                        (unsigned int)__half_as_ushort(__float2half_rn(nn));
            } else {
                nj[s] = wv;                        // bkt arg already decoded
            }
        }
    }
    float ax = 0.f, ay = 0.f;
#pragma unroll
    for (int s = 0; s < 4; ++s) {
        int cb = s << 4;
        if (cb >= m) break;
        int rem = m - cb;
        if (rem > 16) rem = 16;
        int mm = (rem + 7) & ~7;    // padded lanes carry cj=0,nj=0
        for (int jo = 0; jo < mm; jo += 8) {
            int cs[8];
            float ns[8];
            float vs[8];
#pragma unroll
            for (int t = 0; t < 8; ++t) {
                cs[t] = __shfl(cj[s], (q << 4) + jo + t);
                ns[t] = __shfl(nj[s], (q << 4) + jo + t);
            }
#pragma unroll
            for (int t = 0; t < 8; ++t)
                vs[t] = *(const float*)(xin + cs[t] + (ql << 1));
#pragma unroll
            for (int t = 0; t < 8; ++t) {
                float2 a = __half22float2(*(const __half2*)&vs[t]);
                ax += ns[t] * a.x;
                ay += ns[t] * a.y;
            }
        }
    }
    float dr = dinv[node];
    __half2 o = __floats2half2_rn(dr * ax, dr * ay);
    *(__half2*)(xout + ((size_t)node << 5) + (ql << 1)) = o;
}

// MFMA GEMM: out[r][co] = sum_j Xj[r][:] @ Wc[j][:][co], K=4*64, split A.
// A-frag: A[m=lane&15][k=quad*8+i] from (kk<32 ? lo : hi) table row (16B).
// B-frag: B[k=quad*8+i][n=lane&15] from whc[j][n][k..] (transposed, 16B).
// C/D: col=lane&15, row=quad*4+reg.
__global__ __launch_bounds__(256) void gemm_mfma_kernel(
        const __half* __restrict__ x0l, const __half* __restrict__ x0h,
        const __half* __restrict__ x1l, const __half* __restrict__ x1h,
        const __half* __restrict__ x2l, const __half* __restrict__ x2h,
        const __half* __restrict__ x3l, const __half* __restrict__ x3h,
        const _Float16* __restrict__ whc, float* __restrict__ out) {
    const int tid = threadIdx.x;
    const int wv = tid >> 6;
    const int lane = tid & 63;
    const int quad = lane >> 4;
    const int l16 = lane & 15;
    const int mbase = (blockIdx.x << 6) + (wv << 4);
    const __half* slo[4] = {x0l, x1l, x2l, x3l};
    const __half* shi[4] = {x0h, x1h, x2h, x3h};
    f32x4 acc0 = {}, acc1 = {}, acc2 = {}, acc3 = {};
    const int arow = mbase + l16;
    const bool aok = arow < N_NODES;
    const size_t abase = ((size_t)arow << 5) + (quad << 3);
    const half8 zero8 = {};
#pragma unroll
    for (int j = 0; j < 4; ++j) {
#pragma unroll
        for (int kk = 0; kk < 64; kk += 32) {
            const __half* sp = (kk == 0) ? slo[j] : shi[j];
            half8 af = aok ? *(const half8*)(const void*)(sp + abase) : zero8;
            const _Float16* wb = whc + (j << 12) + kk + (quad << 3);
            half8 b0 = *(const half8*)(const void*)(wb + ((0 * 16 + l16) << 6));
            half8 b1 = *(const half8*)(const void*)(wb + ((1 * 16 + l16) << 6));
            half8 b2 = *(const half8*)(const void*)(wb + ((2 * 16 + l16) << 6));
            half8 b3 = *(const half8*)(const void*)(wb + ((3 * 16 + l16) << 6));
            acc0 = __builtin_amdgcn_mfma_f32_16x16x32_f16(af, b0, acc0, 0, 0, 0);
            acc1 = __builtin_amdgcn_mfma_f32_16x16x32_f16(af, b1, acc1, 0, 0, 0);
            acc2 = __builtin_amdgcn_mfma_f32_16x16x32_f16(af, b2, acc2, 0, 0, 0);
            acc3 = __builtin_amdgcn_mfma_f32_16x16x32_f16(af, b3, acc3, 0, 0, 0);
        }
    }
#pragma unroll
    for (int i = 0; i < 4; ++i) {
        int r = mbase + (quad << 2) + i;
        if (r < N_NODES) {
            float* dst = out + ((size_t)r << 6) + l16;
            dst[0]  = acc0[i];
            dst[16] = acc1[i];
            dst[32] = acc2[i];
            dst[48] = acc3[i];
        }
    }
}

extern "C" void kernel_launch(void* const* d_in, const int* in_sizes, int n_in,
                              void* d_out, int out_size, void* d_ws, size_t ws_size,
                              hipStream_t stream) {
    const float* x  = (const float*)d_in[0];
    const int*   ei = (const int*)d_in[1];   // row = ei[0..E), col = ei[E..2E)
    const float* ew = (const float*)d_in[2];
    const float* tf = (const float*)d_in[3];
    const float* tb = (const float*)d_in[4];
    float* out = (float*)d_out;

    const int* row = ei;
    const int* col = ei + N_EDGES;

    // workspace layout (4B words), total ~59 MB
    const int NROWS_PAD = NPART * 256;   // 50176
    const size_t HALF_TBL = (size_t)N_NODES * 32 / 2;   // words per half table
    float* ws = (float*)d_ws;
    size_t off = 0;
    int*    percur = (int*)(ws + off); off += 256;
    uint2*  pedges = (uint2*)(ws + off); off += (size_t)NPART * CAPP * 2;
    unsigned int* bkt  = (unsigned int*)(ws + off); off += (size_t)NROWS_PAD * CAP;
    unsigned int* bkt2 = (unsigned int*)(ws + off); off += (size_t)NROWS_PAD * CAP;
    int*    cnt  = (int*)(ws + off); off += NROWS_PAD;
    float*  dinv = ws + off; off += NROWS_PAD;
    __half* xh0 = (__half*)(ws + off); off += HALF_TBL;
    __half* xh1 = (__half*)(ws + off); off += HALF_TBL;
    __half* tA0 = (__half*)(ws + off); off += HALF_TBL;
    __half* tA1 = (__half*)(ws + off); off += HALF_TBL;
    __half* tB0 = (__half*)(ws + off); off += HALF_TBL;
    __half* tB1 = (__half*)(ws + off); off += HALF_TBL;
    __half* tC0 = (__half*)(ws + off); off += HALF_TBL;
    __half* tC1 = (__half*)(ws + off); off += HALF_TBL;
    _Float16* whc = (_Float16*)(ws + off); off += 4 * 64 * 64 / 2;

    hipMemsetAsync(percur, 0, 256 * sizeof(int), stream);

    scatter2_kernel<<<NEB + XH_BLOCKS + CW_BLOCKS, 1024, 0, stream>>>(
        row, col, ew, percur, pedges, x, xh0, xh1, tf, tb, whc);
    build_kernel<<<NPART, 1024, 0, stream>>>(pedges, percur, bkt, cnt, dinv);

    prop_kernel<true><<<2 * PB, 256, 0, stream>>>(
        xh0, xh1, tA0, tA1, cnt, bkt, bkt2, dinv);            // tx1
    prop_kernel<false><<<2 * PB, 256, 0, stream>>>(
        tA0, tA1, tB0, tB1, cnt, bkt2, bkt2, dinv);           // tx2
    prop_kernel<false><<<2 * PB, 256, 0, stream>>>(
        tB0, tB1, tC0, tC1, cnt, bkt2, bkt2, dinv);           // tx3

    gemm_mfma_kernel<<<GB, 256, 0, stream>>>(
        xh0, xh1, tA0, tA1, tB0, tB1, tC0, tC1, whc, out);
}